// Round 7
// baseline (152.303 us; speedup 1.0000x reference)
//
#include <hip/hip_runtime.h>
#include <math.h>

#define N_G 512
#define IMG_H 324
#define IMG_W 332
#define N_C 120
#define HW (IMG_H*IMG_W)
#define CHUNK 128
#define TSX 21                 // tiles in x (16 px)
#define TSY 81                 // tiles in y (4 px)
#define NT (TSX*TSY)
#define NBLK 768               // 3 persistent blocks per CU

// ws layout (depth-sorted by k_prep):
//   bb  : [512] float4 {xmin, xmax, ymin, ymax}  cull bbox (6-sigma; empty if skip)
//   ps  : [512][8] floats {sx, sy, c00s, c11s, log2op, depth, (src*120)_bits, 0}
//   cnt : int tile queue counter (zeroed by k_prep every launch)

__global__ __launch_bounds__(512) void k_prep(
    const float* __restrict__ pos, const float* __restrict__ scales,
    const float* __restrict__ opac, const float* __restrict__ K,
    const float* __restrict__ E,
    float4* __restrict__ bb, float* __restrict__ ps, int* __restrict__ cnt)
{
  __shared__ float key[N_G];
  const int i = threadIdx.x;
  if (i == 0) *cnt = 0;                        // reset tile queue each launch

  float p0 = pos[i*3+0], p1 = pos[i*3+1], p2 = pos[i*3+2];
  float cam0 = E[0]*p0 + E[1]*p1 + E[2]*p2  + E[3];
  float cam1 = E[4]*p0 + E[5]*p1 + E[6]*p2  + E[7];
  float cam2 = E[8]*p0 + E[9]*p1 + E[10]*p2 + E[11];
  float pr0 = K[0]*cam0 + K[1]*cam1 + K[2]*cam2;
  float pr1 = K[3]*cam0 + K[4]*cam1 + K[5]*cam2;
  float pr2 = K[6]*cam0 + K[7]*cam1 + K[8]*cam2;
  float inv = 1.0f/(pr2 + 1e-6f);
  float sx = pr0*inv, sy = pr1*inv;
  float depth = cam2;

  bool valid = (depth > 0.01f) && (depth < 100.0f)
            && (sx > -100.0f) && (sx < (float)IMG_W + 100.0f)
            && (sy > -100.0f) && (sy < (float)IMG_H + 100.0f);
  bool off = (sx < -(float)IMG_W) || (sx > 2.0f*(float)IMG_W)
          || (sy < -(float)IMG_H) || (sy > 2.0f*(float)IMG_H);
  bool skip = off || (!valid);

  float s0 = scales[i*3+0], s1 = scales[i*3+1];
  float v0 = s0*s0 + 1e-4f, v1 = s1*s1 + 1e-4f;
  const float HL2E = 0.72134752f;              // 0.5*log2(e)
  float c00s = HL2E/v0, c11s = HL2E/v1;
  float op = skip ? 0.0f : opac[i];
  float l2op = __log2f(op);                    // op=0 -> -inf -> exp2 -> 0
  float rx = 6.0f*sqrtf(v0);                   // mahal cutoff 36 (6 sigma)
  float ry = 6.0f*sqrtf(v1);
  float xmin = skip ?  1e9f : sx - rx;
  float xmax = skip ? -1e9f : sx + rx;
  float ymin = skip ?  1e9f : sy - ry;
  float ymax = skip ? -1e9f : sy + ry;

  key[i] = depth;
  __syncthreads();

  int rank = 0;
  #pragma unroll 4
  for (int j = 0; j < N_G; j += 4) {
    float4 k4 = *(const float4*)&key[j];
    rank += (k4.x < depth || (k4.x == depth && j+0 < i)) ? 1 : 0;
    rank += (k4.y < depth || (k4.y == depth && j+1 < i)) ? 1 : 0;
    rank += (k4.z < depth || (k4.z == depth && j+2 < i)) ? 1 : 0;
    rank += (k4.w < depth || (k4.w == depth && j+3 < i)) ? 1 : 0;
  }

  bb[rank] = make_float4(xmin, xmax, ymin, ymax);
  *(float4*)&ps[rank*8]   = make_float4(sx, sy, c00s, c11s);
  *(float4*)&ps[rank*8+4] = make_float4(l2op, depth, __int_as_float(i*N_C), 0.0f);
}

// Persistent-block renderer: 768 blocks pull 16x4-px tiles off a global queue.
// Per tile: build (4-wave ballot compaction) -> 1a araw -> 1b cumprod (wave0)
// -> 2 weighted accumulation (sw-pipelined) -> combine + store.
#define F4(S,i)  S##i = *(const float4*)(row + 4*(i));
#define FETCH(S, jj) { \
    int gs = __float_as_int(prm[(cb+(jj))*8+6]); \
    const float* row = rowbase + gs; \
    F4(S,0) F4(S,1) F4(S,2) F4(S,3) F4(S,4) F4(S,5) F4(S,6) F4(S,7) \
    F4(S,8) F4(S,9) F4(S,10) F4(S,11) F4(S,12) F4(S,13) F4(S,14) \
    w##S = buf[(jj)*64 + lane]; }

#define C4(S,i) \
  { a##i.x = fmaf(w##S, S##i.x, a##i.x); \
    a##i.y = fmaf(w##S, S##i.y, a##i.y); \
    a##i.z = fmaf(w##S, S##i.z, a##i.z); \
    a##i.w = fmaf(w##S, S##i.w, a##i.w); }
#define CONS(S) C4(S,0) C4(S,1) C4(S,2) C4(S,3) C4(S,4) C4(S,5) C4(S,6) \
                C4(S,7) C4(S,8) C4(S,9) C4(S,10) C4(S,11) C4(S,12) C4(S,13) C4(S,14)

#define WR4(i) \
  { slot[4*(i)+0]=a##i.x; slot[4*(i)+1]=a##i.y; \
    slot[4*(i)+2]=a##i.z; slot[4*(i)+3]=a##i.w; }

#define CMB4(i) \
  { float4 t4 = *(const float4*)(tmh + 4*(i)); \
    out[(cbase + 4*(i) + 0)*HW + pixi] = (a##i.x + slot[4*(i)+0] + bgT)*t4.x; \
    out[(cbase + 4*(i) + 1)*HW + pixi] = (a##i.y + slot[4*(i)+1] + bgT)*t4.y; \
    out[(cbase + 4*(i) + 2)*HW + pixi] = (a##i.z + slot[4*(i)+2] + bgT)*t4.z; \
    out[(cbase + 4*(i) + 3)*HW + pixi] = (a##i.w + slot[4*(i)+3] + bgT)*t4.w; }

__global__ __launch_bounds__(256, 2) void k_render(
    const float4* __restrict__ bb, const float* __restrict__ ps,
    int* __restrict__ cnt, const float* __restrict__ spec,
    const float* __restrict__ tm, float* __restrict__ out)
{
  __shared__ float prm[N_G*8];        // compacted hit params (16 KB)
  __shared__ float buf[CHUNK*64];     // araw -> w in place (32 KB); partial stage
  __shared__ float Tcar[64], Dcar[64];
  __shared__ int wcnt[4];
  __shared__ int stile;

  const int tid  = threadIdx.x;
  const int w    = tid >> 6;
  const int lane = tid & 63;
  const int h    = w & 1;             // channel half
  const int s    = w >> 1;            // hit parity
  const int tx = lane & 15, ty = lane >> 4;
  const int cbase = h*60;
  const float* rowbase = spec + cbase;
  const unsigned long long ltm = (1ull << lane) - 1ull;

  for (;;) {
    if (tid == 0) stile = atomicAdd(cnt, 1);
    __syncthreads();
    const int t = stile;
    if (t >= NT) break;
    const int bx = t % TSX, by = t / TSX;

    const int x = bx*16 + tx;
    const int y = by*4 + ty;
    const bool inb = (x < IMG_W) && (y < IMG_H);
    const float px = (float)min(x, IMG_W-1);
    const float py = (float)min(y, IMG_H-1);
    const float wxmin = (float)(bx*16), wxmax = wxmin + 15.0f;
    const float wymin = (float)(by*4),  wymax = wymin + 3.0f;

    // ---- build: 4-wave two-pass ballot compaction (order-preserving) ----
    const int g0 = w*128 + lane;
    const int g1 = g0 + 64;
    float4 b0 = bb[g0], b1 = bb[g1];
    bool h0 = !(b0.x > wxmax || b0.y < wxmin || b0.z > wymax || b0.w < wymin);
    bool h1 = !(b1.x > wxmax || b1.y < wxmin || b1.z > wymax || b1.w < wymin);
    unsigned long long m0 = __ballot(h0), m1 = __ballot(h1);
    int c0 = __popcll(m0), c1 = __popcll(m1);
    if (lane == 0) wcnt[w] = c0 + c1;
    __syncthreads();
    int offw = 0;
    #pragma unroll
    for (int k = 0; k < 4; ++k) if (k < w) offw += wcnt[k];
    const int nh = wcnt[0] + wcnt[1] + wcnt[2] + wcnt[3];
    if (h0) {
      int p = offw + __popcll(m0 & ltm);
      *(float4*)&prm[p*8]   = *(const float4*)&ps[g0*8];
      *(float4*)&prm[p*8+4] = *(const float4*)&ps[g0*8+4];
    }
    if (h1) {
      int p = offw + c0 + __popcll(m1 & ltm);
      *(float4*)&prm[p*8]   = *(const float4*)&ps[g1*8];
      *(float4*)&prm[p*8+4] = *(const float4*)&ps[g1*8+4];
    }
    __syncthreads();

    float T = 1.0f, dacc = 0.0f;      // meaningful in wave 0 (lane = pixel)
    float4 a0={0,0,0,0}, a1={0,0,0,0}, a2={0,0,0,0}, a3={0,0,0,0}, a4={0,0,0,0},
           a5={0,0,0,0}, a6={0,0,0,0}, a7={0,0,0,0}, a8={0,0,0,0}, a9={0,0,0,0},
           a10={0,0,0,0}, a11={0,0,0,0}, a12={0,0,0,0}, a13={0,0,0,0}, a14={0,0,0,0};

    for (int cb = 0; cb < nh; cb += CHUNK) {
      const int nc = min(CHUNK, nh - cb);

      // ---- phase 1a: araw, 4 waves ----
      #pragma unroll 2
      for (int j = w; j < nc; j += 4) {
        float4 p0 = *(const float4*)&prm[(cb+j)*8];     // ds_read_b128
        float4 p1 = *(const float4*)&prm[(cb+j)*8+4];
        float dx = px - p0.x, dy = py - p0.y;
        float m = p0.z*dx*dx + p0.w*dy*dy;              // log2-units
        buf[j*64 + lane] = exp2f(p1.x - m);             // op*exp(-m/2)
      }
      __syncthreads();

      // ---- phase 1b: per-pixel cumprod (wave 0) ----
      if (w == 0) {
        #pragma unroll 4
        for (int j = 0; j < nc; ++j) {
          float a = buf[j*64 + lane];
          float wv = a * T;
          buf[j*64 + lane] = wv;
          T -= wv;
          dacc = fmaf(prm[(cb+j)*8+5], wv, dacc);
        }
      }
      __syncthreads();

      // ---- phase 2: weighted accumulation, 2-deep software pipeline ----
      {
        float4 P0,P1,P2,P3,P4,P5,P6,P7,P8,P9,P10,P11,P12,P13,P14;
        float4 Q0,Q1,Q2,Q3,Q4,Q5,Q6,Q7,Q8,Q9,Q10,Q11,Q12,Q13,Q14;
        float wP, wQ;
        int j = s;
        if (j < nc) FETCH(P, j);
        while (j < nc) {
          int j2 = j + 2;
          if (j2 < nc) FETCH(Q, j2);
          CONS(P);
          j = j2;
          if (j >= nc) break;
          j2 = j + 2;
          if (j2 < nc) FETCH(P, j2);
          CONS(Q);
          j = j2;
        }
      }
      __syncthreads();   // buf reused next chunk
    }

    // ---- epilogue: combine hit-parity partials, store ----
    if (w == 0) { Tcar[lane] = T; Dcar[lane] = dacc; }
    if (s == 1) {
      float* slot = &buf[(h*64 + lane)*61];   // stride 61: conflict-free
      WR4(0)  WR4(1)  WR4(2)  WR4(3)  WR4(4)
      WR4(5)  WR4(6)  WR4(7)  WR4(8)  WR4(9)
      WR4(10) WR4(11) WR4(12) WR4(13) WR4(14)
    }
    __syncthreads();

    if (s == 0 && inb) {
      const int pixi = y*IMG_W + x;
      const float Tf = Tcar[lane];
      const float bgT = Tf;                   // BG*(1 - A_final), BG = 1.0
      const float* tmh = tm + cbase;
      const float* slot = &buf[(h*64 + lane)*61];
      CMB4(0)  CMB4(1)  CMB4(2)  CMB4(3)  CMB4(4)
      CMB4(5)  CMB4(6)  CMB4(7)  CMB4(8)  CMB4(9)
      CMB4(10) CMB4(11) CMB4(12) CMB4(13) CMB4(14)
      if (h == 0) out[N_C*HW + pixi] = Dcar[lane];      // depth image
      else        out[N_C*HW + HW + pixi] = 1.0f - Tf;  // A_final
    }
    __syncthreads();   // protect prm/buf/stile before next tile
  }
}

extern "C" void kernel_launch(void* const* d_in, const int* in_sizes, int n_in,
                              void* d_out, int out_size, void* d_ws, size_t ws_size,
                              hipStream_t stream) {
  const float* pos    = (const float*)d_in[0];
  // d_in[1] rotations: unused by the reference
  const float* scales = (const float*)d_in[2];
  const float* opac   = (const float*)d_in[3];
  const float* spec   = (const float*)d_in[4];
  const float* tm     = (const float*)d_in[5];
  const float* K      = (const float*)d_in[6];
  const float* E      = (const float*)d_in[7];
  float* out = (float*)d_out;

  float4* bb = (float4*)d_ws;
  float*  ps = (float*)(bb + N_G);
  int*    cnt = (int*)((char*)d_ws + N_G*16 + N_G*32);

  k_prep<<<1, 512, 0, stream>>>(pos, scales, opac, K, E, bb, ps, cnt);
  k_render<<<NBLK, 256, 0, stream>>>(bb, ps, cnt, spec, tm, out);
}

// Round 8
// 128.372 us; speedup vs baseline: 1.1864x; 1.1864x over previous
//
#include <hip/hip_runtime.h>
#include <math.h>

#define N_G 512
#define IMG_H 324
#define IMG_W 332
#define N_C 120
#define HW (IMG_H*IMG_W)
#define CHUNK 64
#define TSX 21                 // tiles in x (16 px)
#define TSY 81                 // tiles in y (4 px)
#define NT (TSX*TSY)
#define NBLK 512               // 2 persistent blocks per CU (LDS-capped)

// ws layout (depth-sorted by k_prep):
//   bb  : [512] float4 {xmin, xmax, ymin, ymax}  cull bbox (6-sigma; empty if skip)
//   ps  : [512][8] floats {sx, sy, c00s, c11s, log2op, depth, (src*120)_bits, 0}
//   cnt : int tile queue counter (zeroed by k_prep every launch)

__global__ __launch_bounds__(512) void k_prep(
    const float* __restrict__ pos, const float* __restrict__ scales,
    const float* __restrict__ opac, const float* __restrict__ K,
    const float* __restrict__ E,
    float4* __restrict__ bb, float* __restrict__ ps, int* __restrict__ cnt)
{
  __shared__ float key[N_G];
  const int i = threadIdx.x;
  if (i == 0) *cnt = 0;                        // reset tile queue each launch

  float p0 = pos[i*3+0], p1 = pos[i*3+1], p2 = pos[i*3+2];
  float cam0 = E[0]*p0 + E[1]*p1 + E[2]*p2  + E[3];
  float cam1 = E[4]*p0 + E[5]*p1 + E[6]*p2  + E[7];
  float cam2 = E[8]*p0 + E[9]*p1 + E[10]*p2 + E[11];
  float pr0 = K[0]*cam0 + K[1]*cam1 + K[2]*cam2;
  float pr1 = K[3]*cam0 + K[4]*cam1 + K[5]*cam2;
  float pr2 = K[6]*cam0 + K[7]*cam1 + K[8]*cam2;
  float inv = 1.0f/(pr2 + 1e-6f);
  float sx = pr0*inv, sy = pr1*inv;
  float depth = cam2;

  bool valid = (depth > 0.01f) && (depth < 100.0f)
            && (sx > -100.0f) && (sx < (float)IMG_W + 100.0f)
            && (sy > -100.0f) && (sy < (float)IMG_H + 100.0f);
  bool off = (sx < -(float)IMG_W) || (sx > 2.0f*(float)IMG_W)
          || (sy < -(float)IMG_H) || (sy > 2.0f*(float)IMG_H);
  bool skip = off || (!valid);

  float s0 = scales[i*3+0], s1 = scales[i*3+1];
  float v0 = s0*s0 + 1e-4f, v1 = s1*s1 + 1e-4f;
  const float HL2E = 0.72134752f;              // 0.5*log2(e)
  float c00s = HL2E/v0, c11s = HL2E/v1;
  float op = skip ? 0.0f : opac[i];
  float l2op = __log2f(op);                    // op=0 -> -inf -> exp2 -> 0
  float rx = 6.0f*sqrtf(v0);                   // mahal cutoff 36 (6 sigma)
  float ry = 6.0f*sqrtf(v1);
  float xmin = skip ?  1e9f : sx - rx;
  float xmax = skip ? -1e9f : sx + rx;
  float ymin = skip ?  1e9f : sy - ry;
  float ymax = skip ? -1e9f : sy + ry;

  key[i] = depth;
  __syncthreads();

  int rank = 0;
  #pragma unroll 4
  for (int j = 0; j < N_G; j += 4) {
    float4 k4 = *(const float4*)&key[j];
    rank += (k4.x < depth || (k4.x == depth && j+0 < i)) ? 1 : 0;
    rank += (k4.y < depth || (k4.y == depth && j+1 < i)) ? 1 : 0;
    rank += (k4.z < depth || (k4.z == depth && j+2 < i)) ? 1 : 0;
    rank += (k4.w < depth || (k4.w == depth && j+3 < i)) ? 1 : 0;
  }

  bb[rank] = make_float4(xmin, xmax, ymin, ymax);
  *(float4*)&ps[rank*8]   = make_float4(sx, sy, c00s, c11s);
  *(float4*)&ps[rank*8+4] = make_float4(l2op, depth, __int_as_float(i*N_C), 0.0f);
}

// Persistent blocks pull 16x4-px tiles center-out off a global queue.
// Per tile: build (4-wave ballot compaction into LDS prm) -> chunks of 64:
//   1a: araw[j][px] + stage spec row j -> sbuf[j][0..119]   (parallel, pipelined)
//   1b: wave0 per-pixel cumprod (araw -> w in place)
//   2 : acc[px][c] += w[j][px]*sbuf[j][c]  -- affine LDS reads, issue-bound
#define ACC4(i) \
  { float4 s4 = *(const float4*)(row + 4*(i)); \
    a##i.x = fmaf(wv, s4.x, a##i.x); \
    a##i.y = fmaf(wv, s4.y, a##i.y); \
    a##i.z = fmaf(wv, s4.z, a##i.z); \
    a##i.w = fmaf(wv, s4.w, a##i.w); }

#define WR4(i) \
  { slot[4*(i)+0]=a##i.x; slot[4*(i)+1]=a##i.y; \
    slot[4*(i)+2]=a##i.z; slot[4*(i)+3]=a##i.w; }

#define CMB4(i) \
  { float4 t4 = *(const float4*)(tmh + 4*(i)); \
    out[(cbase + 4*(i) + 0)*HW + pixi] = (a##i.x + slot[4*(i)+0] + bgT)*t4.x; \
    out[(cbase + 4*(i) + 1)*HW + pixi] = (a##i.y + slot[4*(i)+1] + bgT)*t4.y; \
    out[(cbase + 4*(i) + 2)*HW + pixi] = (a##i.z + slot[4*(i)+2] + bgT)*t4.z; \
    out[(cbase + 4*(i) + 3)*HW + pixi] = (a##i.w + slot[4*(i)+3] + bgT)*t4.w; }

__global__ __launch_bounds__(256, 2) void k_render(
    const float4* __restrict__ bb, const float* __restrict__ ps,
    int* __restrict__ cnt, const float* __restrict__ spec,
    const float* __restrict__ tm, float* __restrict__ out)
{
  __shared__ float prm[N_G*8];          // compacted hit params (16 KB)
  __shared__ float buf[CHUNK*64];       // araw -> w in place (16 KB)
  __shared__ float sbuf[CHUNK*N_C];     // staged spectral rows (30.7 KB)
  __shared__ float Tcar[64], Dcar[64];
  __shared__ int wcnt[4];
  __shared__ int stile;

  const int tid  = threadIdx.x;
  const int w    = tid >> 6;
  const int lane = tid & 63;
  const int h    = w & 1;               // channel half
  const int s    = w >> 1;              // hit parity
  const int tx = lane & 15, ty = lane >> 4;
  const int cbase = h*60;
  const unsigned long long ltm = (1ull << lane) - 1ull;

  for (;;) {
    if (tid == 0) stile = atomicAdd(cnt, 1);
    __syncthreads();
    const int t = stile;
    if (t >= NT) break;
    // center-out bijection: hot center tiles are pulled FIRST
    const int jx = t % TSX, ky = t / TSX;
    const int bx = 10 + ((jx & 1) ? ((jx+1)>>1) : -((jx+1)>>1));
    const int by = 40 + ((ky & 1) ? ((ky+1)>>1) : -((ky+1)>>1));

    const int x = bx*16 + tx;
    const int y = by*4 + ty;
    const bool inb = (x < IMG_W) && (y < IMG_H);
    const float px = (float)min(x, IMG_W-1);
    const float py = (float)min(y, IMG_H-1);
    const float wxmin = (float)(bx*16), wxmax = wxmin + 15.0f;
    const float wymin = (float)(by*4),  wymax = wymin + 3.0f;

    // ---- build: 4-wave two-pass ballot compaction (order-preserving) ----
    const int g0 = w*128 + lane;
    const int g1 = g0 + 64;
    float4 b0 = bb[g0], b1 = bb[g1];
    bool h0 = !(b0.x > wxmax || b0.y < wxmin || b0.z > wymax || b0.w < wymin);
    bool h1 = !(b1.x > wxmax || b1.y < wxmin || b1.z > wymax || b1.w < wymin);
    unsigned long long m0 = __ballot(h0), m1 = __ballot(h1);
    int c0 = __popcll(m0), c1 = __popcll(m1);
    if (lane == 0) wcnt[w] = c0 + c1;
    __syncthreads();
    int offw = 0;
    #pragma unroll
    for (int k = 0; k < 4; ++k) if (k < w) offw += wcnt[k];
    const int nh = wcnt[0] + wcnt[1] + wcnt[2] + wcnt[3];
    if (h0) {
      int p = offw + __popcll(m0 & ltm);
      *(float4*)&prm[p*8]   = *(const float4*)&ps[g0*8];
      *(float4*)&prm[p*8+4] = *(const float4*)&ps[g0*8+4];
    }
    if (h1) {
      int p = offw + c0 + __popcll(m1 & ltm);
      *(float4*)&prm[p*8]   = *(const float4*)&ps[g1*8];
      *(float4*)&prm[p*8+4] = *(const float4*)&ps[g1*8+4];
    }
    __syncthreads();

    float T = 1.0f, dacc = 0.0f;        // meaningful in wave 0 (lane = pixel)
    float4 a0={0,0,0,0}, a1={0,0,0,0}, a2={0,0,0,0}, a3={0,0,0,0}, a4={0,0,0,0},
           a5={0,0,0,0}, a6={0,0,0,0}, a7={0,0,0,0}, a8={0,0,0,0}, a9={0,0,0,0},
           a10={0,0,0,0}, a11={0,0,0,0}, a12={0,0,0,0}, a13={0,0,0,0}, a14={0,0,0,0};

    for (int cb = 0; cb < nh; cb += CHUNK) {
      const int nc = min(CHUNK, nh - cb);

      // ---- phase 1a: araw + spectral-row staging (4 waves, pipelined) ----
      #pragma unroll 2
      for (int j = w; j < nc; j += 4) {
        float4 p0 = *(const float4*)&prm[(cb+j)*8];     // ds_read_b128
        float4 p1 = *(const float4*)&prm[(cb+j)*8+4];
        float dx = px - p0.x, dy = py - p0.y;
        float m = p0.z*dx*dx + p0.w*dy*dy;              // log2-units
        buf[j*64 + lane] = exp2f(p1.x - m);             // op*exp(-m/2)
        // stage spec row j: lanes = channel index (coalesced, independent)
        int sbase = __float_as_int(p1.z);               // src*120
        sbuf[j*N_C + lane] = spec[sbase + lane];
        if (lane < N_C - 64) sbuf[j*N_C + 64 + lane] = spec[sbase + 64 + lane];
      }
      __syncthreads();

      // ---- phase 1b: per-pixel cumprod (wave 0) ----
      if (w == 0) {
        #pragma unroll 4
        for (int j = 0; j < nc; ++j) {
          float a = buf[j*64 + lane];
          float wv = a * T;
          buf[j*64 + lane] = wv;
          T -= wv;
          dacc = fmaf(prm[(cb+j)*8+5], wv, dacc);
        }
      }
      __syncthreads();

      // ---- phase 2: weighted accumulation from LDS (affine addresses) ----
      #pragma unroll 2
      for (int j = s; j < nc; j += 2) {
        float wv = buf[j*64 + lane];
        const float* row = &sbuf[j*N_C + cbase];        // broadcast b128 reads
        ACC4(0)  ACC4(1)  ACC4(2)  ACC4(3)  ACC4(4)
        ACC4(5)  ACC4(6)  ACC4(7)  ACC4(8)  ACC4(9)
        ACC4(10) ACC4(11) ACC4(12) ACC4(13) ACC4(14)
      }
      __syncthreads();   // buf/sbuf reused next chunk
    }

    // ---- epilogue: combine hit-parity partials, store ----
    if (w == 0) { Tcar[lane] = T; Dcar[lane] = dacc; }
    if (s == 1) {
      // h=0 partials -> buf (64*61 <= 4096), h=1 -> sbuf
      float* slot = (h == 0 ? buf : sbuf) + lane*61;    // stride 61: conflict-free
      WR4(0)  WR4(1)  WR4(2)  WR4(3)  WR4(4)
      WR4(5)  WR4(6)  WR4(7)  WR4(8)  WR4(9)
      WR4(10) WR4(11) WR4(12) WR4(13) WR4(14)
    }
    __syncthreads();

    if (s == 0 && inb) {
      const int pixi = y*IMG_W + x;
      const float Tf = Tcar[lane];
      const float bgT = Tf;                   // BG*(1 - A_final), BG = 1.0
      const float* tmh = tm + cbase;
      const float* slot = (h == 0 ? buf : sbuf) + lane*61;
      CMB4(0)  CMB4(1)  CMB4(2)  CMB4(3)  CMB4(4)
      CMB4(5)  CMB4(6)  CMB4(7)  CMB4(8)  CMB4(9)
      CMB4(10) CMB4(11) CMB4(12) CMB4(13) CMB4(14)
      if (h == 0) out[N_C*HW + pixi] = Dcar[lane];      // depth image
      else        out[N_C*HW + HW + pixi] = 1.0f - Tf;  // A_final
    }
    __syncthreads();   // protect prm/buf/sbuf/stile before next tile
  }
}

extern "C" void kernel_launch(void* const* d_in, const int* in_sizes, int n_in,
                              void* d_out, int out_size, void* d_ws, size_t ws_size,
                              hipStream_t stream) {
  const float* pos    = (const float*)d_in[0];
  // d_in[1] rotations: unused by the reference
  const float* scales = (const float*)d_in[2];
  const float* opac   = (const float*)d_in[3];
  const float* spec   = (const float*)d_in[4];
  const float* tm     = (const float*)d_in[5];
  const float* K      = (const float*)d_in[6];
  const float* E      = (const float*)d_in[7];
  float* out = (float*)d_out;

  float4* bb = (float4*)d_ws;
  float*  ps = (float*)(bb + N_G);
  int*    cnt = (int*)((char*)d_ws + N_G*16 + N_G*32);

  k_prep<<<1, 512, 0, stream>>>(pos, scales, opac, K, E, bb, ps, cnt);
  k_render<<<NBLK, 256, 0, stream>>>(bb, ps, cnt, spec, tm, out);
}